// Round 9
// baseline (43.283 us; speedup 1.0000x reference)
//
#include <hip/hip_runtime.h>

namespace {
constexpr int B = 4, Te = 512, Td = 128, Den = 256, Dde = 512, U = 128;
constexpr float REMOVE = 1000000.0f;
constexpr float L2E2 = 2.885390081777927f;  // 2*log2(e)

__device__ __forceinline__ unsigned short f2bf(float f) {
  unsigned u = __float_as_uint(f);
  u += 0x7FFFu + ((u >> 16) & 1u);      // RNE
  return (unsigned short)(u >> 16);
}
__device__ __forceinline__ float bf2f(unsigned short h) {
  return __uint_as_float(((unsigned)h) << 16);
}
// acc += tanh(ep+dv)*nv ; tanh = 1 - 2/(exp(2x)+1), inf-safe both tails
__device__ __forceinline__ void tanh_fma(float ep, float dv, float nv, float& acc) {
  float e = __builtin_amdgcn_exp2f((ep + dv) * L2E2);
  float r = __builtin_amdgcn_rcpf(e + 1.0f);
  acc = fmaf(fmaf(-2.0f, r, 1.0f), nv, acc);
}
__device__ __forceinline__ void fma4(const float4& w, float x, float* a) {
  a[0] = fmaf(x, w.x, a[0]); a[1] = fmaf(x, w.y, a[1]);
  a[2] = fmaf(x, w.z, a[2]); a[3] = fmaf(x, w.w, a[3]);
}

// ---------------- K1: projections (384 blocks x 256 thr) ----------------
// blocks 0..255:   8 en rows -> en_pT bf16 U-MAJOR [b][teT:8][u:128][te_in:64]
//                  + masked bf16 en copy
// blocks 256..383: q=blk-256: rt=q>>1 (8 de rows), kh=q&1 (K-half)
//                  -> de_pA/de_pB f32 + de pass-through to out
__global__ __launch_bounds__(256) void proj_kernel(
    const float* __restrict__ en_seq, const float* __restrict__ de_seq,
    const int* __restrict__ mask, const float* __restrict__ w_en,
    const float* __restrict__ w_de, unsigned short* __restrict__ en_pT,
    unsigned short* __restrict__ en_bf, float* __restrict__ de_pA,
    float* __restrict__ de_pB, float* __restrict__ out) {
  __shared__ float xs[2048];            // 8 KiB: [8][256] staging, then [8][128]
  const int blk = blockIdx.x, tid = threadIdx.x;

  if (blk < 256) {
    const int r0 = blk * 8;             // global encoder rows (b*Te+te)
    for (int i = tid; i < 512; i += 256) {    // stage masked + bf16 copy
      int row = i >> 6, c4 = i & 63;
      float m = (float)mask[r0 + row];
      float4 v = *(const float4*)(en_seq + (size_t)(r0 + row) * Den + c4 * 4);
      v.x *= m; v.y *= m; v.z *= m; v.w *= m;
      *(float4*)(xs + row * 256 + c4 * 4) = v;
      ushort4 h; h.x = f2bf(v.x); h.y = f2bf(v.y); h.z = f2bf(v.z); h.w = f2bf(v.w);
      *(ushort4*)(en_bf + (size_t)(r0 + row) * Den + c4 * 4) = h;
    }
    __syncthreads();
    const int rg = tid >> 5, ug = tid & 31, u0 = ug * 4;   // 8 rows x 4 u
    float acc[4] = {0, 0, 0, 0};
#pragma unroll 4
    for (int k = 0; k < 256; k += 4) {
      const float* wp = w_en + (size_t)k * U + u0;
      float4 w0 = *(const float4*)(wp);
      float4 w1 = *(const float4*)(wp + U);
      float4 w2 = *(const float4*)(wp + 2 * U);
      float4 w3 = *(const float4*)(wp + 3 * U);
      float4 xv = *(const float4*)(xs + rg * 256 + k);
      fma4(w0, xv.x, acc); fma4(w1, xv.y, acc);
      fma4(w2, xv.z, acc); fma4(w3, xv.w, acc);
    }
    __syncthreads();                    // all staging reads done
    *(float4*)(xs + rg * 128 + u0) = make_float4(acc[0], acc[1], acc[2], acc[3]);
    __syncthreads();
    {                                   // u-major bf16 write: thread = (u, te-half)
      int u = tid >> 1, half = tid & 1;
      ushort4 h;
      h.x = f2bf(xs[(half * 4 + 0) * 128 + u]);
      h.y = f2bf(xs[(half * 4 + 1) * 128 + u]);
      h.z = f2bf(xs[(half * 4 + 2) * 128 + u]);
      h.w = f2bf(xs[(half * 4 + 3) * 128 + u]);
      int b = r0 >> 9, teT = (r0 >> 6) & 7, tein0 = r0 & 63;
      *(ushort4*)(en_pT + ((size_t)(b * 8 + teT) * 128 + u) * 64 + tein0 + half * 4) = h;
    }
  } else {
    const int q = blk - 256, rt = q >> 1, kh = q & 1;
    const int r0 = rt * 8, k0 = kh * 256;
    for (int i = tid; i < 512; i += 256) {  // stage K-half + pass-through
      int row = i >> 6, c4 = i & 63;
      float4 v = *(const float4*)(de_seq + (size_t)(r0 + row) * Dde + k0 + c4 * 4);
      *(float4*)(xs + row * 256 + c4 * 4) = v;
      *(float4*)(out + (size_t)(r0 + row) * 768 + k0 + c4 * 4) = v;
    }
    __syncthreads();
    const int rg = tid >> 5, ug = tid & 31, u0 = ug * 4;
    float acc[4] = {0, 0, 0, 0};
#pragma unroll 4
    for (int k = 0; k < 256; k += 4) {
      const float* wp = w_de + (size_t)(k0 + k) * U + u0;
      float4 w0 = *(const float4*)(wp);
      float4 w1 = *(const float4*)(wp + U);
      float4 w2 = *(const float4*)(wp + 2 * U);
      float4 w3 = *(const float4*)(wp + 3 * U);
      float4 xv = *(const float4*)(xs + rg * 256 + k);
      fma4(w0, xv.x, acc); fma4(w1, xv.y, acc);
      fma4(w2, xv.z, acc); fma4(w3, xv.w, acc);
    }
    float* dst = kh ? de_pB : de_pA;
    *(float4*)(dst + (size_t)(r0 + rg) * U + u0) =
        make_float4(acc[0], acc[1], acc[2], acc[3]);
  }
}

// ---------------- K2: scores (1024 blocks x 256 thr) ----------------
// grid = (b:4) x (tdT:32 of 4 td) x (teT:8 of 64 te)
// tileT[u:128][te:64] f32 (no pad: stride-64 rows give optimal 8-phase b128)
// thread = (te_pos:16 -> 4 te) x (u_split:16 -> 8 u interleaved); all 4 td.
__global__ __launch_bounds__(256, 4) void score_kernel(
    const unsigned short* __restrict__ en_pT, const float* __restrict__ de_pA,
    const float* __restrict__ de_pB, const float* __restrict__ nu,
    const int* __restrict__ mask, float* __restrict__ mu) {
  __shared__ float tileT[128 * 64];     // 32 KiB; reused as partials scr
  __shared__ float depT[128 * 4];       // [u][td]
  __shared__ float nus[128];
  const int blk = blockIdx.x, tid = threadIdx.x;
  const int teT = blk & 7, tdT = (blk >> 3) & 31, b = blk >> 8;
  const int te0 = teT * 64, td0 = tdT * 4;

  const unsigned short* src = en_pT + (size_t)(b * 8 + teT) * 128 * 64;
#pragma unroll
  for (int j = 0; j < 4; ++j) {         // 1024 x 16B units, coalesced
    int unit = j * 256 + tid;
    int u = unit >> 3, tc = (unit & 7) * 8;
    ushort4 ha = *(const ushort4*)(src + (size_t)u * 64 + tc);
    ushort4 hb = *(const ushort4*)(src + (size_t)u * 64 + tc + 4);
    *(float4*)(tileT + u * 64 + tc) =
        make_float4(bf2f(ha.x), bf2f(ha.y), bf2f(ha.z), bf2f(ha.w));
    *(float4*)(tileT + u * 64 + tc + 4) =
        make_float4(bf2f(hb.x), bf2f(hb.y), bf2f(hb.z), bf2f(hb.w));
  }
  for (int i = tid; i < 512; i += 256) {
    int u = i & 127, td = i >> 7;
    float v = de_pA[((size_t)b * Td + td0 + td) * U + u] +
              de_pB[((size_t)b * Td + td0 + td) * U + u];
    depT[u * 4 + td] = v;
  }
  if (tid < 128) nus[tid] = nu[tid];
  __syncthreads();

  const int tp = tid & 15, us = tid >> 4;
  const int tel0 = tp * 4;
  float a00=0,a01=0,a02=0,a03=0, a10=0,a11=0,a12=0,a13=0;
  float a20=0,a21=0,a22=0,a23=0, a30=0,a31=0,a32=0,a33=0;
#pragma unroll
  for (int jj = 0; jj < 8; ++jj) {
    int u = us + 16 * jj;
    float4 ev = *(const float4*)(tileT + u * 64 + tel0);
    float4 dv = *(const float4*)(depT + u * 4);
    float nv = nus[u];
    tanh_fma(ev.x, dv.x, nv, a00); tanh_fma(ev.y, dv.x, nv, a01);
    tanh_fma(ev.z, dv.x, nv, a02); tanh_fma(ev.w, dv.x, nv, a03);
    tanh_fma(ev.x, dv.y, nv, a10); tanh_fma(ev.y, dv.y, nv, a11);
    tanh_fma(ev.z, dv.y, nv, a12); tanh_fma(ev.w, dv.y, nv, a13);
    tanh_fma(ev.x, dv.z, nv, a20); tanh_fma(ev.y, dv.z, nv, a21);
    tanh_fma(ev.z, dv.z, nv, a22); tanh_fma(ev.w, dv.z, nv, a23);
    tanh_fma(ev.x, dv.w, nv, a30); tanh_fma(ev.y, dv.w, nv, a31);
    tanh_fma(ev.z, dv.w, nv, a32); tanh_fma(ev.w, dv.w, nv, a33);
  }
  __syncthreads();                      // tileT reads done; reuse as scr
  float* scr = tileT;                   // scr[us:16][td:4][te:64]
  {
    float* p = scr + us * 256 + tel0;
    p[0]   = a00; p[1]   = a01; p[2]   = a02; p[3]   = a03;
    p[64]  = a10; p[65]  = a11; p[66]  = a12; p[67]  = a13;
    p[128] = a20; p[129] = a21; p[130] = a22; p[131] = a23;
    p[192] = a30; p[193] = a31; p[194] = a32; p[195] = a33;
  }
  __syncthreads();
  {                                     // reduce over us + bias + mu write
    int td = tid >> 6, te = tid & 63;
    float s = 0.f;
#pragma unroll
    for (int q = 0; q < 16; ++q) s += scr[q * 256 + tid];
    float bias = ((float)mask[b * Te + te0 + te] - 1.0f) * REMOVE;
    mu[((size_t)b * Td + td0 + td) * Te + te0 + te] = s + bias;
  }
}

// ---------------- K3: softmax + weighted sum (256 blocks x 512 thr) ----
// grid = (b:4) x (tdT:64 of 2 td)
__global__ __launch_bounds__(512) void out_kernel(
    const unsigned short* __restrict__ en_bf, const int* __restrict__ mask,
    const float* __restrict__ mu, float* __restrict__ out) {
  __shared__ float al[Te * 2];          // 4 KiB [te][td:2]
  __shared__ float scr[8 * 2 * 256];    // 16 KiB partials
  const int blk = blockIdx.x, tid = threadIdx.x;
  const int b = blk >> 6, tdT = blk & 63;
  const int gtd0 = b * Td + tdT * 2;
  const int wid = tid >> 6, lane = tid & 63;

  if (wid < 2) {                        // softmax of row gtd0+wid over Te=512
    const float* murow = mu + (size_t)(gtd0 + wid) * Te;
    const int* mrow = mask + b * Te;
    float v[8]; float mx = -3.0e38f;
#pragma unroll
    for (int i = 0; i < 8; ++i) { v[i] = murow[lane + i * 64]; mx = fmaxf(mx, v[i]); }
#pragma unroll
    for (int o = 32; o >= 1; o >>= 1) mx = fmaxf(mx, __shfl_xor(mx, o));
    float ss = 0.f;
#pragma unroll
    for (int i = 0; i < 8; ++i) { v[i] = __expf(v[i] - mx); ss += v[i]; }
#pragma unroll
    for (int o = 32; o >= 1; o >>= 1) ss += __shfl_xor(ss, o);
    float inv = 1.0f / ss;
#pragma unroll
    for (int i = 0; i < 8; ++i) {
      int te = lane + i * 64;
      al[te * 2 + wid] = v[i] * inv * (float)mrow[te];   // alpha * mask
    }
  }
  __syncthreads();

  {                                     // wave -> 64 te, lane -> 4 ch (ushort4)
    const int c0 = lane * 4;
    const unsigned short* eb = en_bf + (size_t)b * Te * Den + c0;
    float p0[4] = {0, 0, 0, 0}, p1[4] = {0, 0, 0, 0};
#pragma unroll 4
    for (int t = 0; t < 64; ++t) {
      int te = wid * 64 + t;
      ushort4 h = *(const ushort4*)(eb + (size_t)te * Den);
      float2 av = *(const float2*)(al + te * 2);
      float e0 = bf2f(h.x), e1 = bf2f(h.y), e2 = bf2f(h.z), e3 = bf2f(h.w);
      p0[0] = fmaf(av.x, e0, p0[0]); p0[1] = fmaf(av.x, e1, p0[1]);
      p0[2] = fmaf(av.x, e2, p0[2]); p0[3] = fmaf(av.x, e3, p0[3]);
      p1[0] = fmaf(av.y, e0, p1[0]); p1[1] = fmaf(av.y, e1, p1[1]);
      p1[2] = fmaf(av.y, e2, p1[2]); p1[3] = fmaf(av.y, e3, p1[3]);
    }
    *(float4*)(scr + (wid * 2 + 0) * 256 + c0) = make_float4(p0[0], p0[1], p0[2], p0[3]);
    *(float4*)(scr + (wid * 2 + 1) * 256 + c0) = make_float4(p1[0], p1[1], p1[2], p1[3]);
  }
  __syncthreads();

  {
    int td = tid >> 8, ch = tid & 255;
    float r = 0.f;
#pragma unroll
    for (int w = 0; w < 8; ++w) r += scr[(w * 2 + td) * 256 + ch];
    out[(size_t)(gtd0 + td) * 768 + 512 + ch] = r;
  }
}
} // namespace

extern "C" void kernel_launch(void* const* d_in, const int* in_sizes, int n_in,
                              void* d_out, int out_size, void* d_ws, size_t ws_size,
                              hipStream_t stream) {
  const float* en_seq = (const float*)d_in[0];
  const float* de_seq = (const float*)d_in[1];
  const int*   mask   = (const int*)d_in[2];
  const float* w_en   = (const float*)d_in[3];
  const float* w_de   = (const float*)d_in[4];
  const float* nu     = (const float*)d_in[5];
  float* out = (float*)d_out;

  unsigned short* en_pT = (unsigned short*)d_ws;                 // B*Te*U bf16 (u-major)
  unsigned short* en_bf = en_pT + (size_t)B * Te * U;            // B*Te*Den bf16
  float* de_pA = (float*)(en_bf + (size_t)B * Te * Den);         // B*Td*U f32
  float* de_pB = de_pA + (size_t)B * Td * U;                     // B*Td*U f32
  float* mu    = de_pB + (size_t)B * Td * U;                     // B*Td*Te f32

  hipLaunchKernelGGL(proj_kernel, dim3(384), dim3(256), 0, stream,
                     en_seq, de_seq, mask, w_en, w_de, en_pT, en_bf,
                     de_pA, de_pB, out);
  hipLaunchKernelGGL(score_kernel, dim3(1024), dim3(256), 0, stream,
                     en_pT, de_pA, de_pB, nu, mask, mu);
  hipLaunchKernelGGL(out_kernel, dim3(256), dim3(512), 0, stream,
                     en_bf, mask, mu, out);
}

// Round 10
// 37.598 us; speedup vs baseline: 1.1512x; 1.1512x over previous
//
#include <hip/hip_runtime.h>

namespace {
constexpr int B = 4, Te = 512, Td = 128, Den = 256, Dde = 512, U = 128;
constexpr float REMOVE = 1000000.0f;
constexpr float L2E2 = 2.885390081777927f;  // 2*log2(e)

__device__ __forceinline__ unsigned short f2bf(float f) {
  unsigned u = __float_as_uint(f);
  u += 0x7FFFu + ((u >> 16) & 1u);      // RNE
  return (unsigned short)(u >> 16);
}
__device__ __forceinline__ float bf2f(unsigned short h) {
  return __uint_as_float(((unsigned)h) << 16);
}
// acc += tanh(ep+dv)*nv ; tanh = 1 - 2/(exp(2x)+1), inf-safe both tails
__device__ __forceinline__ void tanh_fma(float ep, float dv, float nv, float& acc) {
  float e = __builtin_amdgcn_exp2f((ep + dv) * L2E2);
  float r = __builtin_amdgcn_rcpf(e + 1.0f);
  acc = fmaf(fmaf(-2.0f, r, 1.0f), nv, acc);
}
__device__ __forceinline__ void fma4(const float4& w, float x, float* a) {
  a[0] = fmaf(x, w.x, a[0]); a[1] = fmaf(x, w.y, a[1]);
  a[2] = fmaf(x, w.z, a[2]); a[3] = fmaf(x, w.w, a[3]);
}

// ---------------- K1: projections (192 blocks x 128 thr) ----------------
// blocks 0..127:  16 en rows, 4r x 4u register tile (4x w reuse) ->
//                 en_pT bf16 U-MAJOR [b][teT:8][u:128][te_in:64] + bf16 en copy
// blocks 128..191: q=blk-128: rt=q>>1 (16 de rows), kh=q&1 (K-half)
//                 -> de_pA/de_pB f32 + de pass-through to out
__global__ __launch_bounds__(128) void proj_kernel(
    const float* __restrict__ en_seq, const float* __restrict__ de_seq,
    const int* __restrict__ mask, const float* __restrict__ w_en,
    const float* __restrict__ w_de, unsigned short* __restrict__ en_pT,
    unsigned short* __restrict__ en_bf, float* __restrict__ de_pA,
    float* __restrict__ de_pB, float* __restrict__ out) {
  __shared__ float xs[4096];            // 16 KiB: [16][256] staging / [16][128] acc
  const int blk = blockIdx.x, tid = threadIdx.x;
  const int rg = tid >> 5, ug = tid & 31, u0 = ug * 4;

  if (blk < 128) {
    const int r0 = blk * 16;            // global encoder rows (b*Te+te)
    for (int i = tid; i < 1024; i += 128) {   // stage masked + bf16 copy
      int row = i >> 6, c4 = i & 63;
      float m = (float)mask[r0 + row];
      float4 v = *(const float4*)(en_seq + (size_t)(r0 + row) * Den + c4 * 4);
      v.x *= m; v.y *= m; v.z *= m; v.w *= m;
      *(float4*)(xs + row * 256 + c4 * 4) = v;
      ushort4 h; h.x = f2bf(v.x); h.y = f2bf(v.y); h.z = f2bf(v.z); h.w = f2bf(v.w);
      *(ushort4*)(en_bf + (size_t)(r0 + row) * Den + c4 * 4) = h;
    }
    __syncthreads();
    float acc[4][4] = {};
    for (int k = 0; k < 256; k += 4) {
      const float* wp = w_en + (size_t)k * U + u0;
      float4 w0 = *(const float4*)(wp);
      float4 w1 = *(const float4*)(wp + U);
      float4 w2 = *(const float4*)(wp + 2 * U);
      float4 w3 = *(const float4*)(wp + 3 * U);
#pragma unroll
      for (int j = 0; j < 4; ++j) {
        float4 xv = *(const float4*)(xs + (rg * 4 + j) * 256 + k);
        fma4(w0, xv.x, acc[j]); fma4(w1, xv.y, acc[j]);
        fma4(w2, xv.z, acc[j]); fma4(w3, xv.w, acc[j]);
      }
    }
    __syncthreads();                    // staging reads done; reuse xs [16][128]
#pragma unroll
    for (int j = 0; j < 4; ++j)
      *(float4*)(xs + (rg * 4 + j) * 128 + u0) =
          make_float4(acc[j][0], acc[j][1], acc[j][2], acc[j][3]);
    __syncthreads();
    {                                   // u-major bf16 write: thread = u
      int u = tid;                      // 0..127
      int b = r0 >> 9, teT = (r0 >> 6) & 7, tein0 = r0 & 63;
      unsigned short* dst =
          en_pT + ((size_t)(b * 8 + teT) * 128 + u) * 64 + tein0;
#pragma unroll
      for (int q = 0; q < 4; ++q) {
        ushort4 h;
        h.x = f2bf(xs[(q * 4 + 0) * 128 + u]);
        h.y = f2bf(xs[(q * 4 + 1) * 128 + u]);
        h.z = f2bf(xs[(q * 4 + 2) * 128 + u]);
        h.w = f2bf(xs[(q * 4 + 3) * 128 + u]);
        *(ushort4*)(dst + q * 4) = h;
      }
    }
  } else {
    const int q = blk - 128, rt = q >> 1, kh = q & 1;
    const int r0 = rt * 16, k0 = kh * 256;
    for (int i = tid; i < 1024; i += 128) {   // stage K-half + pass-through
      int row = i >> 6, c4 = i & 63;
      float4 v = *(const float4*)(de_seq + (size_t)(r0 + row) * Dde + k0 + c4 * 4);
      *(float4*)(xs + row * 256 + c4 * 4) = v;
      *(float4*)(out + (size_t)(r0 + row) * 768 + k0 + c4 * 4) = v;
    }
    __syncthreads();
    float acc[4][4] = {};
    for (int k = 0; k < 256; k += 4) {
      const float* wp = w_de + (size_t)(k0 + k) * U + u0;
      float4 w0 = *(const float4*)(wp);
      float4 w1 = *(const float4*)(wp + U);
      float4 w2 = *(const float4*)(wp + 2 * U);
      float4 w3 = *(const float4*)(wp + 3 * U);
#pragma unroll
      for (int j = 0; j < 4; ++j) {
        float4 xv = *(const float4*)(xs + (rg * 4 + j) * 256 + k);
        fma4(w0, xv.x, acc[j]); fma4(w1, xv.y, acc[j]);
        fma4(w2, xv.z, acc[j]); fma4(w3, xv.w, acc[j]);
      }
    }
    float* dst = kh ? de_pB : de_pA;
#pragma unroll
    for (int j = 0; j < 4; ++j)
      *(float4*)(dst + (size_t)(r0 + rg * 4 + j) * U + u0) =
          make_float4(acc[j][0], acc[j][1], acc[j][2], acc[j][3]);
  }
}

// ---------------- K2: scores (1024 blocks x 256 thr) ----------------
// grid = (b:4) x (tdT:32 of 4 td) x (teT:8 of 64 te)
// tileT[u:128][te:64] f32; thread = (te_pos:16 -> 4 te) x (u_split:16); 4 td.
__global__ __launch_bounds__(256, 4) void score_kernel(
    const unsigned short* __restrict__ en_pT, const float* __restrict__ de_pA,
    const float* __restrict__ de_pB, const float* __restrict__ nu,
    const int* __restrict__ mask, float* __restrict__ mu) {
  __shared__ float tileT[128 * 64];     // 32 KiB; reused as partials scr
  __shared__ float depT[128 * 4];       // [u][td]
  __shared__ float nus[128];
  const int blk = blockIdx.x, tid = threadIdx.x;
  const int teT = blk & 7, tdT = (blk >> 3) & 31, b = blk >> 8;
  const int te0 = teT * 64, td0 = tdT * 4;

  const unsigned short* src = en_pT + (size_t)(b * 8 + teT) * 128 * 64;
#pragma unroll
  for (int j = 0; j < 4; ++j) {         // 1024 x 16B units, coalesced
    int unit = j * 256 + tid;
    int u = unit >> 3, tc = (unit & 7) * 8;
    ushort4 ha = *(const ushort4*)(src + (size_t)u * 64 + tc);
    ushort4 hb = *(const ushort4*)(src + (size_t)u * 64 + tc + 4);
    *(float4*)(tileT + u * 64 + tc) =
        make_float4(bf2f(ha.x), bf2f(ha.y), bf2f(ha.z), bf2f(ha.w));
    *(float4*)(tileT + u * 64 + tc + 4) =
        make_float4(bf2f(hb.x), bf2f(hb.y), bf2f(hb.z), bf2f(hb.w));
  }
  for (int i = tid; i < 512; i += 256) {
    int u = i & 127, td = i >> 7;
    float v = de_pA[((size_t)b * Td + td0 + td) * U + u] +
              de_pB[((size_t)b * Td + td0 + td) * U + u];
    depT[u * 4 + td] = v;
  }
  if (tid < 128) nus[tid] = nu[tid];
  __syncthreads();

  const int tp = tid & 15, us = tid >> 4;
  const int tel0 = tp * 4;
  float a00=0,a01=0,a02=0,a03=0, a10=0,a11=0,a12=0,a13=0;
  float a20=0,a21=0,a22=0,a23=0, a30=0,a31=0,a32=0,a33=0;
#pragma unroll
  for (int jj = 0; jj < 8; ++jj) {
    int u = us + 16 * jj;
    float4 ev = *(const float4*)(tileT + u * 64 + tel0);
    float4 dv = *(const float4*)(depT + u * 4);
    float nv = nus[u];
    tanh_fma(ev.x, dv.x, nv, a00); tanh_fma(ev.y, dv.x, nv, a01);
    tanh_fma(ev.z, dv.x, nv, a02); tanh_fma(ev.w, dv.x, nv, a03);
    tanh_fma(ev.x, dv.y, nv, a10); tanh_fma(ev.y, dv.y, nv, a11);
    tanh_fma(ev.z, dv.y, nv, a12); tanh_fma(ev.w, dv.y, nv, a13);
    tanh_fma(ev.x, dv.z, nv, a20); tanh_fma(ev.y, dv.z, nv, a21);
    tanh_fma(ev.z, dv.z, nv, a22); tanh_fma(ev.w, dv.z, nv, a23);
    tanh_fma(ev.x, dv.w, nv, a30); tanh_fma(ev.y, dv.w, nv, a31);
    tanh_fma(ev.z, dv.w, nv, a32); tanh_fma(ev.w, dv.w, nv, a33);
  }
  __syncthreads();                      // tileT reads done; reuse as scr
  float* scr = tileT;                   // scr[us:16][td:4][te:64]
  {
    float* p = scr + us * 256 + tel0;
    p[0]   = a00; p[1]   = a01; p[2]   = a02; p[3]   = a03;
    p[64]  = a10; p[65]  = a11; p[66]  = a12; p[67]  = a13;
    p[128] = a20; p[129] = a21; p[130] = a22; p[131] = a23;
    p[192] = a30; p[193] = a31; p[194] = a32; p[195] = a33;
  }
  __syncthreads();
  {                                     // reduce over us + bias + mu write
    int td = tid >> 6, te = tid & 63;
    float s = 0.f;
#pragma unroll
    for (int q2 = 0; q2 < 16; ++q2) s += scr[q2 * 256 + tid];
    float bias = ((float)mask[b * Te + te0 + te] - 1.0f) * REMOVE;
    mu[((size_t)b * Td + td0 + td) * Te + te0 + te] = s + bias;
  }
}

// ---------------- K3: softmax + weighted sum (256 blocks x 512 thr) ----
// grid = (b:4) x (tdT:32 of 4 td) x (chHalf:2 of 128)
__global__ __launch_bounds__(512) void out_kernel(
    const unsigned short* __restrict__ en_bf, const int* __restrict__ mask,
    const float* __restrict__ mu, float* __restrict__ out) {
  __shared__ float al[Te * 4];          // 8 KiB, [te][td]
  __shared__ float part[8 * 4 * 128];   // 16 KiB
  const int blk = blockIdx.x, tid = threadIdx.x;
  const int chH = blk & 1, tdT = (blk >> 1) & 31, b = blk >> 6;
  const int td0 = tdT * 4;
  const int wid = tid >> 6, lane = tid & 63;

  if (wid < 4) {                        // softmax of row td0+wid over Te=512
    const float* murow = mu + (size_t)(b * Td + td0 + wid) * Te;
    const int* mrow = mask + b * Te;
    float v[8]; float mx = -3.0e38f;
#pragma unroll
    for (int i = 0; i < 8; ++i) { v[i] = murow[lane + i * 64]; mx = fmaxf(mx, v[i]); }
#pragma unroll
    for (int o = 32; o >= 1; o >>= 1) mx = fmaxf(mx, __shfl_xor(mx, o));
    float ss = 0.f;
#pragma unroll
    for (int i = 0; i < 8; ++i) { v[i] = __expf(v[i] - mx); ss += v[i]; }
#pragma unroll
    for (int o = 32; o >= 1; o >>= 1) ss += __shfl_xor(ss, o);
    float inv = 1.0f / ss;
#pragma unroll
    for (int i = 0; i < 8; ++i) {
      int te = lane + i * 64;
      al[te * 4 + wid] = v[i] * inv * (float)mrow[te];   // alpha * mask
    }
  }
  __syncthreads();

  {                                     // weighted sum: wave -> 64 te, lane -> 2 ch
    const int c0 = chH * 128 + lane * 2;
    const unsigned short* eb = en_bf + (size_t)b * Te * Den + c0;
    float a00 = 0, a01 = 0, a10 = 0, a11 = 0, a20 = 0, a21 = 0, a30 = 0, a31 = 0;
#pragma unroll 4
    for (int t = 0; t < 64; ++t) {
      int te = wid * 64 + t;
      ushort2 h = *(const ushort2*)(eb + (size_t)te * Den);
      float4 av = *(const float4*)(al + te * 4);
      float e0 = bf2f(h.x), e1 = bf2f(h.y);
      a00 = fmaf(av.x, e0, a00); a01 = fmaf(av.x, e1, a01);
      a10 = fmaf(av.y, e0, a10); a11 = fmaf(av.y, e1, a11);
      a20 = fmaf(av.z, e0, a20); a21 = fmaf(av.z, e1, a21);
      a30 = fmaf(av.w, e0, a30); a31 = fmaf(av.w, e1, a31);
    }
    *(float2*)(part + (wid * 4 + 0) * 128 + lane * 2) = make_float2(a00, a01);
    *(float2*)(part + (wid * 4 + 1) * 128 + lane * 2) = make_float2(a10, a11);
    *(float2*)(part + (wid * 4 + 2) * 128 + lane * 2) = make_float2(a20, a21);
    *(float2*)(part + (wid * 4 + 3) * 128 + lane * 2) = make_float2(a30, a31);
  }
  __syncthreads();

  {
    int td = tid >> 7, cc = tid & 127;
    float r = 0.f;
#pragma unroll
    for (int w = 0; w < 8; ++w) r += part[(w * 4 + td) * 128 + cc];
    out[(size_t)(b * Td + td0 + td) * 768 + 512 + chH * 128 + cc] = r;
  }
}
} // namespace

extern "C" void kernel_launch(void* const* d_in, const int* in_sizes, int n_in,
                              void* d_out, int out_size, void* d_ws, size_t ws_size,
                              hipStream_t stream) {
  const float* en_seq = (const float*)d_in[0];
  const float* de_seq = (const float*)d_in[1];
  const int*   mask   = (const int*)d_in[2];
  const float* w_en   = (const float*)d_in[3];
  const float* w_de   = (const float*)d_in[4];
  const float* nu     = (const float*)d_in[5];
  float* out = (float*)d_out;

  unsigned short* en_pT = (unsigned short*)d_ws;                 // B*Te*U bf16 (u-major)
  unsigned short* en_bf = en_pT + (size_t)B * Te * U;            // B*Te*Den bf16
  float* de_pA = (float*)(en_bf + (size_t)B * Te * Den);         // B*Td*U f32
  float* de_pB = de_pA + (size_t)B * Td * U;                     // B*Td*U f32
  float* mu    = de_pB + (size_t)B * Td * U;                     // B*Td*Te f32

  hipLaunchKernelGGL(proj_kernel, dim3(192), dim3(128), 0, stream,
                     en_seq, de_seq, mask, w_en, w_de, en_pT, en_bf,
                     de_pA, de_pB, out);
  hipLaunchKernelGGL(score_kernel, dim3(1024), dim3(256), 0, stream,
                     en_pT, de_pA, de_pB, nu, mask, mu);
  hipLaunchKernelGGL(out_kernel, dim3(256), dim3(512), 0, stream,
                     en_bf, mask, mu, out);
}